// Round 20
// baseline (293.321 us; speedup 1.0000x reference)
//
#include <hip/hip_runtime.h>
#include <hip/hip_bf16.h>
#include <cfloat>

#define HD 128

typedef float f32x4 __attribute__((ext_vector_type(4)));
typedef __bf16 bf16x8 __attribute__((ext_vector_type(8)));

// -------- Kernel 1: segment bounds (batch is sorted) --------
__global__ void seg_bounds_kernel(const int* __restrict__ batch, int n, int nseg,
                                  int* __restrict__ seg_start) {
  int b = blockIdx.x * blockDim.x + threadIdx.x;
  if (b > nseg) return;
  if (b == nseg) { seg_start[b] = n; return; }
  int lo = 0, hi = n;
  while (lo < hi) {
    int mid = (lo + hi) >> 1;
    if (batch[mid] < b) lo = mid + 1; else hi = mid;
  }
  seg_start[b] = lo;
}

// 16-lane-row rotate (DPP) for reductions.
template <int CTRL>
__device__ __forceinline__ float dpp_ror(float v) {
  return __int_as_float(__builtin_amdgcn_update_dpp(
      0, __float_as_int(v), CTRL, 0xF, 0xF, true));
}

// -------- Kernel 2: FULLY-FUSED, LDS-ring edition (race-hardened) ----------
// 128-thread blocks (2 waves), 64KB dynamic LDS: per-wave 4-slot x 8KB h ring
// fed by global_load_lds. 2 blocks/CU -> 1 wave/SIMD; W1 held entirely in
// registers (128 VGPR). Depth-3 prefetch (~4k cy cover).
// RACE FIX vs R19: an explicit s_waitcnt lgkmcnt(0) sits between the slot's
// ds_reads (all consumed by then) and the STAGE that overwrites the same
// slot — the LDS-DMA write cannot land before the reads have sampled their
// bytes (DS pipe and DMA write port are otherwise unordered).
// Per tile: vmcnt(24) counted wait -> 8 swizzled ds_read_b128 (chunk c of
// row r holds global chunk c^r -> 2-way banks, free) -> cvt -> lgkmcnt(0)
// fence -> STAGE(t+4, clamped rows, branchless) -> hf-halved MFMA + trans
// epilogue -> fixed-shift softmax weight -> fp32 pooling from LDS bytes.
// Tail: DPP reduce + fused MLP head (sG aliases ring after vmcnt(0) drain).

#define STAGE_TILE(T, SLOT)                                                 \
  {                                                                         \
    _Pragma("unroll")                                                       \
    for (int j_ = 0; j_ < 8; ++j_) {                                        \
      const int rj_ = 2 * j_ + (lane >> 5);                                 \
      const int grow_ = s0 + min((T) * 16 + rj_, lenm1);                    \
      const float* gp_ =                                                    \
          h + (size_t)grow_ * HD + (((lane & 31) ^ rj_) << 2);              \
      __builtin_amdgcn_global_load_lds(                                     \
          gp_, (void*)(dynLds + wid * 32768 + (SLOT) * 8192 + j_ * 1024),   \
          16, 0, 0);                                                        \
    }                                                                       \
  }

#define PROC_TILE(T)                                                        \
  {                                                                         \
    const bool valid_ = ((T) * 16 + lr) < len;                              \
    const char* tb_ = dynLds + wid * 32768 + ((T) & 3) * 8192 + lr * 512;   \
    float hv_[32];                                                          \
    bf16x8 aq_[4];                                                          \
    _Pragma("unroll")                                                       \
    for (int kt = 0; kt < 4; ++kt) {                                        \
      const int q0_ = (8 * kt + 2 * kl) ^ lr;                               \
      const float4 v0_ = *reinterpret_cast<const float4*>(tb_ + q0_ * 16);  \
      const float4 v1_ =                                                    \
          *reinterpret_cast<const float4*>(tb_ + (q0_ ^ 1) * 16);           \
      hv_[8*kt+0] = v0_.x; hv_[8*kt+1] = v0_.y;                             \
      hv_[8*kt+2] = v0_.z; hv_[8*kt+3] = v0_.w;                             \
      hv_[8*kt+4] = v1_.x; hv_[8*kt+5] = v1_.y;                             \
      hv_[8*kt+6] = v1_.z; hv_[8*kt+7] = v1_.w;                             \
      bf16x8 a_;                                                            \
      a_[0] = (__bf16)v0_.x; a_[1] = (__bf16)v0_.y;                         \
      a_[2] = (__bf16)v0_.z; a_[3] = (__bf16)v0_.w;                         \
      a_[4] = (__bf16)v1_.x; a_[5] = (__bf16)v1_.y;                         \
      a_[6] = (__bf16)v1_.z; a_[7] = (__bf16)v1_.w;                         \
      aq_[kt] = a_;                                                         \
    }                                                                       \
    /* WAR fence: all 8 ds_reads of this slot have returned before the */   \
    /* DMA that overwrites the slot is issued. */                           \
    asm volatile("s_waitcnt lgkmcnt(0)" ::: "memory");                      \
    STAGE_TILE((T) + 4, (T) & 3)                                            \
    float p2_[4] = {0.f, 0.f, 0.f, 0.f};                                    \
    _Pragma("unroll")                                                       \
    for (int hf = 0; hf < 2; ++hf) {                                        \
      f32x4 macc_[4];                                                       \
      _Pragma("unroll")                                                     \
      for (int fh = 0; fh < 4; ++fh) macc_[fh] = (f32x4){0.f, 0.f, 0.f, 0.f}; \
      __builtin_amdgcn_s_setprio(1);                                        \
      _Pragma("unroll")                                                     \
      for (int kt = 0; kt < 4; ++kt) {                                      \
        _Pragma("unroll")                                                   \
        for (int fh = 0; fh < 4; ++fh)                                      \
          macc_[fh] = __builtin_amdgcn_mfma_f32_16x16x32_bf16(              \
              aq_[kt], Bf[4 * hf + fh][kt], macc_[fh], 0, 0, 0);            \
      }                                                                     \
      __builtin_amdgcn_s_setprio(0);                                        \
      _Pragma("unroll")                                                     \
      for (int fh = 0; fh < 4; ++fh) {                                      \
        const int f_ = 4 * hf + fh;                                         \
        _Pragma("unroll")                                                   \
        for (int r = 0; r < 4; ++r) {                                       \
          const float xe_ = fmaf(LOG2E2, macc_[fh][r], b1s[f_]);            \
          const float e_ = exp2f(xe_);                                      \
          const float t_ = __builtin_amdgcn_rcpf(1.f + e_);                 \
          p2_[r] = fmaf(t_, w2r[f_], p2_[r]);                               \
        }                                                                   \
      }                                                                     \
    }                                                                       \
    _Pragma("unroll")                                                       \
    for (int r = 0; r < 4; ++r) {                                           \
      p2_[r] += dpp_ror<0x121>(p2_[r]);                                     \
      p2_[r] += dpp_ror<0x122>(p2_[r]);                                     \
      p2_[r] += dpp_ror<0x124>(p2_[r]);                                     \
      p2_[r] += dpp_ror<0x128>(p2_[r]);                                     \
    }                                                                       \
    const int rr_ = lr & 3;                                                 \
    const float psel_ =                                                     \
        rr_ == 0 ? p2_[0] : (rr_ == 1 ? p2_[1] : (rr_ == 2 ? p2_[2]         \
                                                            : p2_[3]));     \
    const float sc_ = __shfl(psel_, ((lr >> 2) << 4) | (lr & 3), 64);       \
    const float w_ = valid_ ? exp2f(sc_ * NEG2LOG2E) : 0.f;                 \
    s += w_;                                                                \
    _Pragma("unroll")                                                       \
    for (int j = 0; j < 32; ++j) {                                          \
      acc[j] = fmaf(hv_[j], w_, acc[j]);                                    \
      gm[j] = fmaxf(gm[j], hv_[j]);                                         \
    }                                                                       \
  }

__global__ __launch_bounds__(128, 1) void fused_pool_kernel(
    const float* __restrict__ h, const float* __restrict__ w1,
    const float* __restrict__ b1, const float* __restrict__ w2,
    const int* __restrict__ seg_start, int B,
    const float* __restrict__ w1m, const float* __restrict__ b1m,
    const float* __restrict__ w2m, const float* __restrict__ b2m,
    float* __restrict__ out)
{
  extern __shared__ __align__(16) char dynLds[];  // 64KB: 2 waves x 4x8KB ring

  const int tid  = threadIdx.x;
  const int lane = tid & 63;
  const int wid  = tid >> 6;   // 0..1
  const int lr   = lane & 15;
  const int kl   = lane >> 4;

  // One-time: stage W1^T bf16 into dynLds[0,32K) (aliases wave0's ring),
  // gather the full B operand into registers, then reuse the space.
  {
    __bf16* sWt = reinterpret_cast<__bf16*>(dynLds);
    for (int i = tid; i < HD * HD / 4; i += 128) {
      const int k = i >> 5;
      const int c4 = (i & 31) << 2;
      const float4 v = reinterpret_cast<const float4*>(w1)[i];
      const float vv[4] = {v.x, v.y, v.z, v.w};
#pragma unroll
      for (int q = 0; q < 4; ++q) sWt[(c4 + q) * HD + k] = (__bf16)vv[q];
    }
  }
  __syncthreads();
  bf16x8 Bf[8][4];
#pragma unroll
  for (int f = 0; f < 8; ++f)
#pragma unroll
    for (int kt = 0; kt < 4; ++kt)
      Bf[f][kt] = *reinterpret_cast<const bf16x8*>(
          reinterpret_cast<const __bf16*>(dynLds) +
          (16 * f + lr) * HD + 32 * kt + 8 * kl);
  __syncthreads();  // W1 area now reusable as wave0's ring

  const float LOG2E2    = 2.88539008177792681f;   // 2*log2(e)
  const float NEG2LOG2E = -2.88539008177792681f;  // -2*log2(e)

  float w2r[8], b1s[8];
#pragma unroll
  for (int f = 0; f < 8; ++f) {
    w2r[f] = w2[16 * f + lr];
    b1s[f] = LOG2E2 * b1[16 * f + lr];
  }

  for (int b = blockIdx.x * 2 + wid; b < B; b += gridDim.x * 2) {
    const int s0  = seg_start[b];
    const int len = seg_start[b + 1] - s0;
    const int lenm1 = len - 1;
    const int nt  = (len + 15) >> 4;

    float s = 0.f;
    float acc[32], gm[32];
#pragma unroll
    for (int j = 0; j < 32; ++j) { acc[j] = 0.f; gm[j] = -FLT_MAX; }

    if (nt > 0) {
      STAGE_TILE(0, 0)
      STAGE_TILE(1, 1)
      STAGE_TILE(2, 2)
      STAGE_TILE(3, 3)
      for (int t = 0; t < nt; ++t) {
        // oldest tile (t) complete; tiles t+1..t+3 stay in flight
        asm volatile("s_waitcnt vmcnt(24)" ::: "memory");
        PROC_TILE(t)
      }
    }

    // Final reduce across the 16 lr lanes (features depend only on kl).
#pragma unroll
    for (int st = 1; st <= 8; st <<= 1) {
      if (st == 1) {
        s += dpp_ror<0x121>(s);
#pragma unroll
        for (int j = 0; j < 32; ++j) {
          acc[j] += dpp_ror<0x121>(acc[j]);
          gm[j] = fmaxf(gm[j], dpp_ror<0x121>(gm[j]));
        }
      } else if (st == 2) {
        s += dpp_ror<0x122>(s);
#pragma unroll
        for (int j = 0; j < 32; ++j) {
          acc[j] += dpp_ror<0x122>(acc[j]);
          gm[j] = fmaxf(gm[j], dpp_ror<0x122>(gm[j]));
        }
      } else if (st == 4) {
        s += dpp_ror<0x124>(s);
#pragma unroll
        for (int j = 0; j < 32; ++j) {
          acc[j] += dpp_ror<0x124>(acc[j]);
          gm[j] = fmaxf(gm[j], dpp_ror<0x124>(gm[j]));
        }
      } else {
        s += dpp_ror<0x128>(s);
#pragma unroll
        for (int j = 0; j < 32; ++j) {
          acc[j] += dpp_ror<0x128>(acc[j]);
          gm[j] = fmaxf(gm[j], dpp_ror<0x128>(gm[j]));
        }
      }
    }

    // Drain stray (overrun) stages before aliasing the ring as sG.
    asm volatile("s_waitcnt vmcnt(0)" ::: "memory");
    float* sG = reinterpret_cast<float*>(dynLds + wid * 32768);

    if (lr == 0) {  // lanes 0,16,32,48: one per kl group
      const float invS = (s > 0.f) ? 1.f / s : 0.f;
#pragma unroll
      for (int kt = 0; kt < 4; ++kt) {
        const int fb = 32 * kt + 8 * kl;
        float4 va, vb, ma, mb;
        va.x = acc[8*kt+0]*invS; va.y = acc[8*kt+1]*invS;
        va.z = acc[8*kt+2]*invS; va.w = acc[8*kt+3]*invS;
        vb.x = acc[8*kt+4]*invS; vb.y = acc[8*kt+5]*invS;
        vb.z = acc[8*kt+6]*invS; vb.w = acc[8*kt+7]*invS;
        ma.x = gm[8*kt+0]; ma.y = gm[8*kt+1]; ma.z = gm[8*kt+2]; ma.w = gm[8*kt+3];
        mb.x = gm[8*kt+4]; mb.y = gm[8*kt+5]; mb.z = gm[8*kt+6]; mb.w = gm[8*kt+7];
        *reinterpret_cast<float4*>(&sG[fb])           = va;
        *reinterpret_cast<float4*>(&sG[fb + 4])       = vb;
        *reinterpret_cast<float4*>(&sG[128 + fb])     = ma;
        *reinterpret_cast<float4*>(&sG[128 + fb + 4]) = mb;
      }
    }
    asm volatile("s_waitcnt lgkmcnt(0)" ::: "memory");  // wave-internal flush

    // ---- MLP tail: 64 lanes x 2 hidden units; coalesced w1m streams ----
    {
      const int u = lane;
      float a0 = b1m[u], a1 = b1m[u + 64];
      const float* wp0 = w1m + u;
#pragma unroll 8
      for (int kq = 0; kq < 64; ++kq) {
        const float4 g4 = *reinterpret_cast<const float4*>(&sG[4 * kq]);
        const float* wk = wp0 + (size_t)(4 * kq) * HD;
        a0 = fmaf(g4.x, wk[0],            a0);
        a1 = fmaf(g4.x, wk[64],           a1);
        a0 = fmaf(g4.y, wk[HD],           a0);
        a1 = fmaf(g4.y, wk[HD + 64],      a1);
        a0 = fmaf(g4.z, wk[2 * HD],       a0);
        a1 = fmaf(g4.z, wk[2 * HD + 64],  a1);
        a0 = fmaf(g4.w, wk[3 * HD],       a0);
        a1 = fmaf(g4.w, wk[3 * HD + 64],  a1);
      }
      float v = fmaxf(a0, 0.f) * w2m[u] + fmaxf(a1, 0.f) * w2m[u + 64];
#pragma unroll
      for (int off = 32; off >= 1; off >>= 1) v += __shfl_xor(v, off, 64);
      if (lane == 0) out[b] = v + b2m[0];
    }
  }
}

extern "C" void kernel_launch(void* const* d_in, const int* in_sizes, int n_in,
                              void* d_out, int out_size, void* d_ws, size_t ws_size,
                              hipStream_t stream) {
  const float* h       = (const float*)d_in[0];
  const int*   batch   = (const int*)d_in[1];
  const float* gate_w1 = (const float*)d_in[2];
  const float* gate_b1 = (const float*)d_in[3];
  const float* gate_w2 = (const float*)d_in[4];
  const float* mlp_w1  = (const float*)d_in[6];
  const float* mlp_b1  = (const float*)d_in[7];
  const float* mlp_w2  = (const float*)d_in[8];
  const float* mlp_b2  = (const float*)d_in[9];
  float* out = (float*)d_out;

  const int N = in_sizes[0] / HD;   // 1048576
  const int B = out_size;           // 4096

  int* seg = (int*)d_ws;            // B+1 ints

  seg_bounds_kernel<<<(B + 256) / 256, 256, 0, stream>>>(batch, N, B, seg);
  // 1024 blocks x 2 waves, 64KB dynamic LDS each -> 2 blocks/CU,
  // 1 wave/SIMD, depth-3 LDS-ring prefetch; 2 segments per wave.
  fused_pool_kernel<<<1024, 128, 65536, stream>>>(h, gate_w1, gate_b1,
                                                  gate_w2, seg, B, mlp_w1,
                                                  mlp_b1, mlp_w2, mlp_b2, out);
}

// Round 21
// 158.085 us; speedup vs baseline: 1.8555x; 1.8555x over previous
//
#include <hip/hip_runtime.h>
#include <hip/hip_bf16.h>
#include <cfloat>

#define HD 128

typedef float f32x4 __attribute__((ext_vector_type(4)));
typedef __bf16 bf16x8 __attribute__((ext_vector_type(8)));

// -------- Kernel 1: segment bounds (batch is sorted) --------
__global__ void seg_bounds_kernel(const int* __restrict__ batch, int n, int nseg,
                                  int* __restrict__ seg_start) {
  int b = blockIdx.x * blockDim.x + threadIdx.x;
  if (b > nseg) return;
  if (b == nseg) { seg_start[b] = n; return; }
  int lo = 0, hi = n;
  while (lo < hi) {
    int mid = (lo + hi) >> 1;
    if (batch[mid] < b) lo = mid + 1; else hi = mid;
  }
  seg_start[b] = lo;
}

// 16-lane-row rotate (DPP): dst lane i gets lane (i+N) mod 16 within its row.
template <int CTRL>
__device__ __forceinline__ float dpp_ror(float v) {
  return __int_as_float(__builtin_amdgcn_update_dpp(
      0, __float_as_int(v), CTRL, 0xF, 0xF, true));
}

// -------- Kernel 2: FULLY-FUSED gate-score + softmax + pooling + MLP -------
// R16/R18 configuration, verbatim (verified 158.0 us, absmax 9.77e-4).
// Design-space bracket (all measured worse): triple-buffer reg (R6/R10/R17:
// spill), LDS-ring @1 wave/SIMD (R19/R20: WAR-fence serialization, 293us),
// reg-diet occupancy (R8), un-halved macc (R13), operand swap (R12),
// dynamic queue (R7).
// Hot loop: one wave per segment (static, 4096 waves), double-buffered h
// (hA/hB fp32, 64 regs), branchless 2-deep loop (clamped rows; overrun
// PROCs are no-ops, w=0), hf-HALVED macc (trans epilogue of half 0 overlaps
// MFMA burst of half 1), per-kt transient cvt, setprio per half, per-tile
// DPP row reduce.
// Score: score = sumW2 - 2*sum(w2/(1+e^{2x})); consts cancel in softmax,
// |score - const| <= 2*sum|w2| ~ 11 -> fixed shift is fp32-safe.
// Tail: per-segment MLP head fused: g staged in per-wave LDS slot
// (wave-internal, lgkmcnt-ordered), 64 lanes x 2 hidden units, coalesced
// w1m dword streams (L2-resident).

#define LOAD_TILE(BUF, T)                                                   \
  {                                                                         \
    const int nIt_ = (T) * 16 + lr;                                         \
    const size_t row_ = (size_t)s0 + (size_t)min(nIt_, lenm1);              \
    const float* hp_ = h + row_ * HD + 8 * kl;                              \
    _Pragma("unroll")                                                       \
    for (int kt = 0; kt < 4; ++kt) {                                        \
      *reinterpret_cast<float4*>(&BUF[8 * kt]) =                            \
          *reinterpret_cast<const float4*>(hp_ + 32 * kt);                  \
      *reinterpret_cast<float4*>(&BUF[8 * kt + 4]) =                        \
          *reinterpret_cast<const float4*>(hp_ + 32 * kt + 4);              \
    }                                                                       \
  }

#define PROC_TILE(BUF, T)                                                   \
  {                                                                         \
    const bool valid_ = ((T) * 16 + lr) < len;                              \
    /* opaque: keep B-frag reads inside the loop (anti-LICM) */             \
    asm volatile("" : "+v"(Cb));                                            \
    float p2_[4] = {0.f, 0.f, 0.f, 0.f};                                    \
    _Pragma("unroll")                                                       \
    for (int hf = 0; hf < 2; ++hf) {                                        \
      f32x4 macc_[4];                                                       \
      _Pragma("unroll")                                                     \
      for (int fh = 0; fh < 4; ++fh) macc_[fh] = (f32x4){0.f, 0.f, 0.f, 0.f}; \
      __builtin_amdgcn_s_setprio(1);                                        \
      _Pragma("unroll")                                                     \
      for (int kt = 0; kt < 4; ++kt) {                                      \
        bf16x8 acur_;                                                       \
        _Pragma("unroll")                                                   \
        for (int j = 0; j < 8; ++j) acur_[j] = (__bf16)BUF[8 * kt + j];     \
        const char* bp_ = reinterpret_cast<const char*>(sWt) +              \
                          (Cb + ((kt ^ hi2) << 6)) + hf * 16384;            \
        bf16x8 bfr_[4];                                                     \
        _Pragma("unroll")                                                   \
        for (int fh = 0; fh < 4; ++fh)                                      \
          bfr_[fh] = *reinterpret_cast<const bf16x8*>(bp_ + fh * 4096);     \
        _Pragma("unroll")                                                   \
        for (int fh = 0; fh < 4; ++fh)                                      \
          macc_[fh] = __builtin_amdgcn_mfma_f32_16x16x32_bf16(              \
              acur_, bfr_[fh], macc_[fh], 0, 0, 0);                         \
      }                                                                     \
      __builtin_amdgcn_s_setprio(0);                                        \
      _Pragma("unroll")                                                     \
      for (int fh = 0; fh < 4; ++fh) {                                      \
        const int f_ = 4 * hf + fh;                                         \
        _Pragma("unroll")                                                   \
        for (int r = 0; r < 4; ++r) {                                       \
          const float xe_ = fmaf(LOG2E2, macc_[fh][r], b1s[f_]);            \
          const float e_ = exp2f(xe_);                                      \
          const float t_ = __builtin_amdgcn_rcpf(1.f + e_);                 \
          p2_[r] = fmaf(t_, w2r[f_], p2_[r]);                               \
        }                                                                   \
      }                                                                     \
    }                                                                       \
    /* 16-lane row sum via DPP rotate-adds (1+2+4+8 covers 16) */           \
    _Pragma("unroll")                                                       \
    for (int r = 0; r < 4; ++r) {                                           \
      p2_[r] += dpp_ror<0x121>(p2_[r]);                                     \
      p2_[r] += dpp_ror<0x122>(p2_[r]);                                     \
      p2_[r] += dpp_ror<0x124>(p2_[r]);                                     \
      p2_[r] += dpp_ror<0x128>(p2_[r]);                                     \
    }                                                                       \
    const int rr_ = lr & 3;                                                 \
    const float psel_ =                                                     \
        rr_ == 0 ? p2_[0] : (rr_ == 1 ? p2_[1] : (rr_ == 2 ? p2_[2]         \
                                                            : p2_[3]));     \
    const float sc_ = __shfl(psel_, ((lr >> 2) << 4) | (lr & 3), 64);       \
    const float w_ = valid_ ? exp2f(sc_ * NEG2LOG2E) : 0.f;                 \
    s += w_;                                                                \
    _Pragma("unroll")                                                       \
    for (int j = 0; j < 32; ++j) {                                          \
      acc[j] = fmaf(BUF[j], w_, acc[j]);                                    \
      gm[j] = fmaxf(gm[j], BUF[j]);                                         \
    }                                                                       \
  }

__global__ __launch_bounds__(256, 2) void fused_pool_kernel(
    const float* __restrict__ h, const float* __restrict__ w1,
    const float* __restrict__ b1, const float* __restrict__ w2,
    const int* __restrict__ seg_start, int B,
    const float* __restrict__ w1m, const float* __restrict__ b1m,
    const float* __restrict__ w2m, const float* __restrict__ b2m,
    float* __restrict__ out)
{
  __shared__ __bf16 sWt[HD * HD];  // W1^T bf16, XOR-swizzled 16B slots (32 KB)
  __shared__ float sG[4][256];     // per-wave g slot: [0..128)=attn,[128..)=max

  for (int i = threadIdx.x; i < HD * HD / 4; i += 256) {
    const int k = i >> 5;
    const int c4 = (i & 31) << 2;
    const float4 v = reinterpret_cast<const float4*>(w1)[i];
    const float vv[4] = {v.x, v.y, v.z, v.w};
#pragma unroll
    for (int q = 0; q < 4; ++q) {
      const int c = c4 + q;
      sWt[c * HD + ((((k >> 3) ^ (c & 15)) << 3) | (k & 7))] = (__bf16)vv[q];
    }
  }
  __syncthreads();

  const float LOG2E2    = 2.88539008177792681f;   // 2*log2(e)
  const float NEG2LOG2E = -2.88539008177792681f;  // -2*log2(e)

  const int lane = threadIdx.x & 63;
  const int wid  = threadIdx.x >> 6;
  const int lr   = lane & 15;
  const int kl   = lane >> 4;

  float w2r[8], b1s[8];
#pragma unroll
  for (int f = 0; f < 8; ++f) {
    w2r[f] = w2[16 * f + lr];
    b1s[f] = LOG2E2 * b1[16 * f + lr];
  }

  // B-fragment LDS byte offsets: addr(hf,kt,fh) = Cb + ((kt^hi2)<<6)
  //   + hf*16384 + fh*4096   (c & 15 == lr for every fragment column).
  const int hi2 = (lr >> 2) & 3;
  int Cb = lr * 256 + ((kl ^ (lr & 3)) << 4);

  const int segStride = gridDim.x * 4;
  for (int b = blockIdx.x * 4 + wid; b < B; b += segStride) {
    const int s0  = seg_start[b];
    const int len = seg_start[b + 1] - s0;
    const int lenm1 = len - 1;
    const int nt  = (len + 15) >> 4;

    float s = 0.f;
    float acc[32], gm[32];
#pragma unroll
    for (int j = 0; j < 32; ++j) { acc[j] = 0.f; gm[j] = -FLT_MAX; }

    if (nt > 0) {
      float hA[32], hB[32];
      LOAD_TILE(hA, 0)
      LOAD_TILE(hB, 1)
      for (int t = 0; t < nt; t += 2) {   // branchless; overruns are no-ops
        PROC_TILE(hA, t)
        LOAD_TILE(hA, t + 2)
        PROC_TILE(hB, t + 1)
        LOAD_TILE(hB, t + 3)
      }
    }

    // Final reduce across the 16 lr lanes, on the VALU (DPP rotate-ops).
#pragma unroll
    for (int st = 1; st <= 8; st <<= 1) {
      if (st == 1) {
        s += dpp_ror<0x121>(s);
#pragma unroll
        for (int j = 0; j < 32; ++j) {
          acc[j] += dpp_ror<0x121>(acc[j]);
          gm[j] = fmaxf(gm[j], dpp_ror<0x121>(gm[j]));
        }
      } else if (st == 2) {
        s += dpp_ror<0x122>(s);
#pragma unroll
        for (int j = 0; j < 32; ++j) {
          acc[j] += dpp_ror<0x122>(acc[j]);
          gm[j] = fmaxf(gm[j], dpp_ror<0x122>(gm[j]));
        }
      } else if (st == 4) {
        s += dpp_ror<0x124>(s);
#pragma unroll
        for (int j = 0; j < 32; ++j) {
          acc[j] += dpp_ror<0x124>(acc[j]);
          gm[j] = fmaxf(gm[j], dpp_ror<0x124>(gm[j]));
        }
      } else {
        s += dpp_ror<0x128>(s);
#pragma unroll
        for (int j = 0; j < 32; ++j) {
          acc[j] += dpp_ror<0x128>(acc[j]);
          gm[j] = fmaxf(gm[j], dpp_ror<0x128>(gm[j]));
        }
      }
    }

    // Stage g into this wave's LDS slot (wave-internal, lgkmcnt-ordered).
    if (lr == 0) {  // lanes 0,16,32,48: one per kl group
      const float invS = (s > 0.f) ? 1.f / s : 0.f;
#pragma unroll
      for (int kt = 0; kt < 4; ++kt) {
        const int fb = 32 * kt + 8 * kl;
        float4 va, vb, ma, mb;
        va.x = acc[8*kt+0]*invS; va.y = acc[8*kt+1]*invS;
        va.z = acc[8*kt+2]*invS; va.w = acc[8*kt+3]*invS;
        vb.x = acc[8*kt+4]*invS; vb.y = acc[8*kt+5]*invS;
        vb.z = acc[8*kt+6]*invS; vb.w = acc[8*kt+7]*invS;
        ma.x = gm[8*kt+0]; ma.y = gm[8*kt+1]; ma.z = gm[8*kt+2]; ma.w = gm[8*kt+3];
        mb.x = gm[8*kt+4]; mb.y = gm[8*kt+5]; mb.z = gm[8*kt+6]; mb.w = gm[8*kt+7];
        *reinterpret_cast<float4*>(&sG[wid][fb])           = va;
        *reinterpret_cast<float4*>(&sG[wid][fb + 4])       = vb;
        *reinterpret_cast<float4*>(&sG[wid][128 + fb])     = ma;
        *reinterpret_cast<float4*>(&sG[wid][128 + fb + 4]) = mb;
      }
    }
    asm volatile("s_waitcnt lgkmcnt(0)" ::: "memory");  // wave-internal flush

    // ---- MLP tail: 64 lanes x 2 hidden units; coalesced w1m streams ----
    {
      const int u = lane;
      float a0 = b1m[u], a1 = b1m[u + 64];
      const float* wp0 = w1m + u;
#pragma unroll 8
      for (int kq = 0; kq < 64; ++kq) {
        const float4 g4 = *reinterpret_cast<const float4*>(&sG[wid][4 * kq]);
        const float* wk = wp0 + (size_t)(4 * kq) * HD;
        a0 = fmaf(g4.x, wk[0],            a0);
        a1 = fmaf(g4.x, wk[64],           a1);
        a0 = fmaf(g4.y, wk[HD],           a0);
        a1 = fmaf(g4.y, wk[HD + 64],      a1);
        a0 = fmaf(g4.z, wk[2 * HD],       a0);
        a1 = fmaf(g4.z, wk[2 * HD + 64],  a1);
        a0 = fmaf(g4.w, wk[3 * HD],       a0);
        a1 = fmaf(g4.w, wk[3 * HD + 64],  a1);
      }
      float v = fmaxf(a0, 0.f) * w2m[u] + fmaxf(a1, 0.f) * w2m[u + 64];
#pragma unroll
      for (int off = 32; off >= 1; off >>= 1) v += __shfl_xor(v, off, 64);
      if (lane == 0) out[b] = v + b2m[0];
    }
  }
}

extern "C" void kernel_launch(void* const* d_in, const int* in_sizes, int n_in,
                              void* d_out, int out_size, void* d_ws, size_t ws_size,
                              hipStream_t stream) {
  const float* h       = (const float*)d_in[0];
  const int*   batch   = (const int*)d_in[1];
  const float* gate_w1 = (const float*)d_in[2];
  const float* gate_b1 = (const float*)d_in[3];
  const float* gate_w2 = (const float*)d_in[4];
  const float* mlp_w1  = (const float*)d_in[6];
  const float* mlp_b1  = (const float*)d_in[7];
  const float* mlp_w2  = (const float*)d_in[8];
  const float* mlp_b2  = (const float*)d_in[9];
  float* out = (float*)d_out;

  const int N = in_sizes[0] / HD;   // 1048576
  const int B = out_size;           // 4096

  int* seg = (int*)d_ws;            // B+1 ints

  seg_bounds_kernel<<<(B + 256) / 256, 256, 0, stream>>>(batch, N, B, seg);
  // 1024 blocks x 4 waves = 4096 waves -> one segment per wave (static).
  fused_pool_kernel<<<1024, 256, 0, stream>>>(h, gate_w1, gate_b1, gate_w2,
                                              seg, B, mlp_w1, mlp_b1, mlp_w2,
                                              mlp_b2, out);
}